// Round 1
// baseline (105.322 us; speedup 1.0000x reference)
//
#include <hip/hip_runtime.h>
#include <math.h>

// B=4096, K=128, D=256.
// out[b,d] = sqrt(1-e) * sum_k p_k * (x - a*c)/var,  var = 1 + e*(s^2-1)
// lp_k = -0.5*S1 - 128*ln2*S2 + ln w_k  (k-uniform const dropped)
//   S1 = sum_d diff^2/var, S2 = sum_d log2(var)
// Quad-combined division (1 rcp / 4 d-tuples) + packed 2xf32 math: the two
// f2 lanes are two batch rows (g-pair) sharing every table value.
//
// This revision: 512-thread blocks (was 256) at the same G=4 rows/block.
// Grid stays 1024 blocks -> 4 blocks/CU x 8 waves = 32 waves/CU (was 16),
// doubling latency hiding for the L2-serviced table streams at ZERO extra
// L2 traffic. Pass 1 splits D into 4 quarters per k; pass 2 splits K into
// 2 halves per d with an LDS partial-sum combine. Per-element math is
// unchanged (same fma tree, same quad rcp, same 16-d log2 groups).

constexpr int Kc = 128;
constexpr int Dc = 256;
constexpr int G  = 4;   // batch rows per block (2 f2 pairs)

typedef float f2 __attribute__((ext_vector_type(2)));
typedef float f4 __attribute__((ext_vector_type(4)));

static __device__ __forceinline__ f2 fma2(f2 a, f2 b, f2 c) {
    return __builtin_elementwise_fma(a, b, c);
}
static __device__ __forceinline__ f2 splat2(float s) { return (f2){s, s}; }

// prep: CA8[(d>>2)][k][8] = {c0,c1,c2,c3,A0,A1,A2,A3} (pass-1, transposed);
//       P2[k*Dc+d] = {c, A} (pass-2), A = s^2-1.
__global__ void prep_kernel(const float* __restrict__ centers,
                            const float* __restrict__ stds,
                            float* __restrict__ CA8, f2* __restrict__ P2) {
    int idx = blockIdx.x * blockDim.x + threadIdx.x;   // k*Dc + d, read-coalesced
    if (idx >= Kc * Dc) return;
    int k = idx >> 8;
    int d = idx & (Dc - 1);
    float c = centers[idx];
    float s = stds[idx];
    float A = s * s - 1.0f;
    int o = (d >> 2) * (Kc * 8) + k * 8 + (d & 3);
    CA8[o]     = c;
    CA8[o + 4] = A;
    P2[idx] = (f2){c, A};
}

__global__ __launch_bounds__(512, 8) void score_kernel(
    const float* __restrict__ x, const float* __restrict__ t,
    const float* __restrict__ weights,
    const float* __restrict__ CA8, const f2* __restrict__ P2,
    float* __restrict__ out)
{
    const int b0  = blockIdx.x * G;
    const int tid = threadIdx.x;

    __shared__ __align__(16) float xT[Dc][G];   // x transposed
    __shared__ float part1[G][4][Kc];           // 4 D-quarters
    __shared__ float partL[G][4][Kc];
    __shared__ __align__(16) float peT[Kc][G];  // unnormalized softmax numerators
    __shared__ float wmax[G][2];
    __shared__ float wsum[G][2];
    __shared__ __align__(16) float Opart[G][Dc]; // pass-2 k-half-1 partials

    // per-row scalars
    float e[G], na[G], sg[G];
    #pragma unroll
    for (int g = 0; g < G; ++g) {
        float tt = t[b0 + g];
        float Bt = fmaf(9.95f * tt, tt, 0.1f * tt);
        float ee = __expf(-Bt);
        e[g]  = ee;
        na[g] = -sqrtf(ee);
        sg[g] = sqrtf(1.0f - ee);
    }
    f2 e2[2]  = {{e[0], e[1]}, {e[2], e[3]}};
    f2 na2[2] = {{na[0], na[1]}, {na[2], na[3]}};
    const f2 one2 = {1.0f, 1.0f};

    {   // stage x: 512 threads, each loads 2 of the 4 rows
        const int dd = tid & (Dc - 1);
        const int gh = tid >> 8;                 // 0 or 1
        xT[dd][gh]     = x[(b0 + gh) * Dc + dd];
        xT[dd][gh + 2] = x[(b0 + gh + 2) * Dc + dd];
    }
    __syncthreads();

    // ---------------- pass 1: thread = (k, quarter-of-D) ----------------
    const int kk      = tid & (Kc - 1);
    const int quarter = tid >> 7;                // 0..3
    const int dbase   = quarter * (Dc / 4);      // 64 d's per thread

    const f4* xTv = (const f4*)(&xT[0][0]);

    f2 acc1[2] = {{0.f, 0.f}, {0.f, 0.f}};
    float accL[G] = {0.f, 0.f, 0.f, 0.f};

    for (int grp = 0; grp < 4; ++grp) {
        f2 prod[2] = {{1.f, 1.f}, {1.f, 1.f}};
        #pragma unroll
        for (int q = 0; q < 4; ++q) {
            const int d0 = dbase + (grp * 4 + q) * 4;
            const float* base = CA8 + ((size_t)(d0 >> 2) * Kc + kk) * 8;
            f4 c4 = *(const f4*)base;          // dwordx4, coalesced over kk
            f4 A4 = *(const f4*)(base + 4);    // same addr + imm 16
            f4 xv0 = xTv[d0 + 0];              // LDS b128 broadcast (d uniform)
            f4 xv1 = xTv[d0 + 1];
            f4 xv2 = xTv[d0 + 2];
            f4 xv3 = xTv[d0 + 3];
            #pragma unroll
            for (int p = 0; p < 2; ++p) {
                f2 ep = e2[p], nap = na2[p];
                f2 x0 = {xv0[2*p], xv0[2*p+1]};
                f2 x1 = {xv1[2*p], xv1[2*p+1]};
                f2 x2 = {xv2[2*p], xv2[2*p+1]};
                f2 x3 = {xv3[2*p], xv3[2*p+1]};
                f2 v0 = fma2(ep, splat2(A4[0]), one2);   // var in [0.25,1]
                f2 v1 = fma2(ep, splat2(A4[1]), one2);
                f2 v2 = fma2(ep, splat2(A4[2]), one2);
                f2 v3 = fma2(ep, splat2(A4[3]), one2);
                f2 f0 = fma2(nap, splat2(c4[0]), x0);
                f2 f1 = fma2(nap, splat2(c4[1]), x1);
                f2 f2_ = fma2(nap, splat2(c4[2]), x2);
                f2 f3 = fma2(nap, splat2(c4[3]), x3);
                f2 s0 = f0 * f0, s1 = f1 * f1, s2 = f2_ * f2_, s3 = f3 * f3;
                f2 d01 = v0 * v1, d23 = v2 * v3;
                f2 n01 = fma2(s1, v0, s0 * v1);
                f2 n23 = fma2(s3, v2, s2 * v3);
                f2 den = d01 * d23;                      // >= 0.25^4
                f2 num = fma2(n23, d01, n01 * d23);
                f2 r = {__builtin_amdgcn_rcpf(den[0]),
                        __builtin_amdgcn_rcpf(den[1])};
                acc1[p] = fma2(num, r, acc1[p]);
                prod[p] = prod[p] * den;
            }
        }
        accL[0] += __log2f(prod[0][0]);        // 1 log per 16 d per g
        accL[1] += __log2f(prod[0][1]);
        accL[2] += __log2f(prod[1][0]);
        accL[3] += __log2f(prod[1][1]);
    }
    #pragma unroll
    for (int p = 0; p < 2; ++p) {
        part1[2*p  ][quarter][kk] = acc1[p][0];
        part1[2*p+1][quarter][kk] = acc1[p][1];
    }
    #pragma unroll
    for (int g = 0; g < G; ++g)
        partL[g][quarter][kk] = accL[g];
    __syncthreads();

    // ---------------- softmax over k (threads < K, 2 full waves) ----------------
    float lpv[G];
    if (tid < Kc) {
        float lw = __logf(weights[tid]);
        #pragma unroll
        for (int g = 0; g < G; ++g) {
            float S1 = (part1[g][0][tid] + part1[g][1][tid])
                     + (part1[g][2][tid] + part1[g][3][tid]);
            float S2 = (partL[g][0][tid] + partL[g][1][tid])
                     + (partL[g][2][tid] + partL[g][3][tid]);
            lpv[g] = fmaf(-0.5f, S1, fmaf(-88.72283911167299f, S2, lw)); // 128*ln2
            float m = lpv[g];
            #pragma unroll
            for (int off = 32; off > 0; off >>= 1)
                m = fmaxf(m, __shfl_xor(m, off, 64));
            if ((tid & 63) == 0) wmax[g][tid >> 6] = m;
        }
    }
    __syncthreads();
    if (tid < Kc) {
        #pragma unroll
        for (int g = 0; g < G; ++g) {
            float m  = fmaxf(wmax[g][0], wmax[g][1]);
            float pe = __expf(lpv[g] - m);
            peT[tid][g] = pe;                  // unnormalized; 1/Z in epilogue
            float s = pe;
            #pragma unroll
            for (int off = 32; off > 0; off >>= 1)
                s += __shfl_xor(s, off, 64);
            if ((tid & 63) == 0) wsum[g][tid >> 6] = s;
        }
    }
    __syncthreads();

    // ---------------- pass 2: thread = (k-half, d) ----------------
    const int dd    = tid & (Dc - 1);
    const int khalf = tid >> 8;                // 0 or 1
    f4 xvv = xTv[dd];
    f2 xp[2] = {{xvv[0], xvv[1]}, {xvv[2], xvv[3]}};
    f2 O[2] = {{0.f, 0.f}, {0.f, 0.f}};
    const f4* peTv = (const f4*)(&peT[0][0]);
    const f2* pp = P2 + dd;

    const int kq0 = khalf * 16;
    for (int kq = kq0; kq < kq0 + 16; ++kq) {
        const int k0 = kq * 4;
        f2 ca0 = pp[(k0 + 0) * Dc];            // dwordx2 {c,A}, coalesced
        f2 ca1 = pp[(k0 + 1) * Dc];
        f2 ca2 = pp[(k0 + 2) * Dc];
        f2 ca3 = pp[(k0 + 3) * Dc];
        f4 p0 = peTv[k0 + 0];                  // LDS b128 broadcast
        f4 p1 = peTv[k0 + 1];
        f4 p2 = peTv[k0 + 2];
        f4 p3 = peTv[k0 + 3];
        #pragma unroll
        for (int p = 0; p < 2; ++p) {
            f2 ep = e2[p], nap = na2[p];
            f2 v0 = fma2(ep, splat2(ca0[1]), one2);
            f2 v1 = fma2(ep, splat2(ca1[1]), one2);
            f2 v2 = fma2(ep, splat2(ca2[1]), one2);
            f2 v3 = fma2(ep, splat2(ca3[1]), one2);
            f2 f0 = fma2(nap, splat2(ca0[0]), xp[p]);
            f2 f1 = fma2(nap, splat2(ca1[0]), xp[p]);
            f2 f2_ = fma2(nap, splat2(ca2[0]), xp[p]);
            f2 f3 = fma2(nap, splat2(ca3[0]), xp[p]);
            f2 u0 = (f2){p0[2*p], p0[2*p+1]} * f0;
            f2 u1 = (f2){p1[2*p], p1[2*p+1]} * f1;
            f2 u2 = (f2){p2[2*p], p2[2*p+1]} * f2_;
            f2 u3 = (f2){p3[2*p], p3[2*p+1]} * f3;
            f2 d01 = v0 * v1, d23 = v2 * v3;
            f2 n01 = fma2(u1, v0, u0 * v1);
            f2 n23 = fma2(u3, v2, u2 * v3);
            f2 den = d01 * d23;
            f2 num = fma2(n23, d01, n01 * d23);
            f2 r = {__builtin_amdgcn_rcpf(den[0]),
                    __builtin_amdgcn_rcpf(den[1])};
            O[p] = fma2(num, r, O[p]);
        }
    }

    if (khalf) {
        #pragma unroll
        for (int p = 0; p < 2; ++p) {
            #pragma unroll
            for (int j = 0; j < 2; ++j)
                Opart[2*p + j][dd] = O[p][j];
        }
    }
    __syncthreads();
    if (!khalf) {
        #pragma unroll
        for (int p = 0; p < 2; ++p) {
            #pragma unroll
            for (int j = 0; j < 2; ++j) {
                int g = 2 * p + j;
                float Z  = wsum[g][0] + wsum[g][1];
                float Ov = O[p][j] + Opart[g][dd];   // (k-half0) + (k-half1)
                out[(b0 + g) * Dc + dd] = sg[g] * __builtin_amdgcn_rcpf(Z) * Ov;
            }
        }
    }
}

extern "C" void kernel_launch(void* const* d_in, const int* in_sizes, int n_in,
                              void* d_out, int out_size, void* d_ws, size_t ws_size,
                              hipStream_t stream) {
    const float* x       = (const float*)d_in[0];
    const float* t       = (const float*)d_in[1];
    const float* centers = (const float*)d_in[2];
    const float* stds    = (const float*)d_in[3];
    const float* weights = (const float*)d_in[4];
    float* outp = (float*)d_out;

    float* CA8 = (float*)d_ws;                    // [D/4][K][8]  (256 KB)
    f2*    P2  = (f2*)(CA8 + Kc * Dc * 2);        // [K][D] {c,A} (256 KB)

    const int B = in_sizes[1];                    // 4096

    prep_kernel<<<(Kc * Dc + 255) / 256, 256, 0, stream>>>(centers, stds, CA8, P2);
    score_kernel<<<B / G, 512, 0, stream>>>(x, t, weights, CA8, P2, outp);
}

// Round 2
// 100.582 us; speedup vs baseline: 1.0471x; 1.0471x over previous
//
#include <hip/hip_runtime.h>
#include <math.h>

// B=4096, K=128, D=256.
// out[b,d] = sqrt(1-e) * sum_k p_k * (x - a*c)/var,  var = 1 + e*(s^2-1)
// lp_k = -0.5*S1 - 128*ln2*S2 + ln w_k  (k-uniform const dropped)
//   S1 = sum_d diff^2/var, S2 = sum_d log2(var)
//
// This revision: G=8 rows/block (was 4) at 512 threads. Round-1 showed the
// kernel is NOT latency-bound (2x waves -> 0% change): the limiter is per-CU
// VMEM line processing on the table streams (pass-1 b128 loads at 32B lane
// stride touch 32 cachelines/instr). Doubling rows/block halves table
// traffic per CU at identical per-CU VALU work. Per-element math unchanged
// (same fma tree, quad rcp, 16-d log2 groups).

constexpr int Kc = 128;
constexpr int Dc = 256;
constexpr int G  = 8;   // batch rows per block (4 f2 pairs)

typedef float f2 __attribute__((ext_vector_type(2)));
typedef float f4 __attribute__((ext_vector_type(4)));

static __device__ __forceinline__ f2 fma2(f2 a, f2 b, f2 c) {
    return __builtin_elementwise_fma(a, b, c);
}
static __device__ __forceinline__ f2 splat2(float s) { return (f2){s, s}; }

// prep: CA8[(d>>2)][k][8] = {c0,c1,c2,c3,A0,A1,A2,A3} (pass-1, transposed);
//       P2[k*Dc+d] = {c, A} (pass-2), A = s^2-1.
__global__ void prep_kernel(const float* __restrict__ centers,
                            const float* __restrict__ stds,
                            float* __restrict__ CA8, f2* __restrict__ P2) {
    int idx = blockIdx.x * blockDim.x + threadIdx.x;   // k*Dc + d, read-coalesced
    if (idx >= Kc * Dc) return;
    int k = idx >> 8;
    int d = idx & (Dc - 1);
    float c = centers[idx];
    float s = stds[idx];
    float A = s * s - 1.0f;
    int o = (d >> 2) * (Kc * 8) + k * 8 + (d & 3);
    CA8[o]     = c;
    CA8[o + 4] = A;
    P2[idx] = (f2){c, A};
}

__global__ __launch_bounds__(512, 4) void score_kernel(
    const float* __restrict__ x, const float* __restrict__ t,
    const float* __restrict__ weights,
    const float* __restrict__ CA8, const f2* __restrict__ P2,
    float* __restrict__ out)
{
    const int b0  = blockIdx.x * G;
    const int tid = threadIdx.x;

    __shared__ __align__(16) float xT[Dc][G];    // 8 KB, x transposed
    __shared__ float part1[G][4][Kc];            // 16 KB
    __shared__ float partL[G][4][Kc];            // 16 KB
    __shared__ __align__(16) float peT[Kc][G];   // 4 KB, softmax numerators
    __shared__ float wmax[G][2];
    __shared__ float wsum[G][2];
    __shared__ __align__(16) float Opart[G][Dc]; // 8 KB, pass-2 k-half-1 partials

    // per-row scalars, packed as 4 f2 pairs
    f2 e2[4], na2[4];
    #pragma unroll
    for (int p = 0; p < 4; ++p) {
        #pragma unroll
        for (int j = 0; j < 2; ++j) {
            float tt = t[b0 + 2 * p + j];
            float Bt = fmaf(9.95f * tt, tt, 0.1f * tt);
            float ee = __expf(-Bt);
            e2[p][j]  = ee;
            na2[p][j] = -sqrtf(ee);
        }
    }
    const f2 one2 = {1.0f, 1.0f};

    {   // stage x: 512 threads, each loads 4 of the 8 rows
        const int dd = tid & (Dc - 1);
        const int h  = tid >> 8;                 // 0 or 1
        #pragma unroll
        for (int j = 0; j < 4; ++j)
            xT[dd][h * 4 + j] = x[(b0 + h * 4 + j) * Dc + dd];
    }
    __syncthreads();

    // ---------------- pass 1: thread = (k, quarter-of-D) ----------------
    const int kk      = tid & (Kc - 1);
    const int quarter = tid >> 7;                // 0..3
    const int dbase   = quarter * (Dc / 4);      // 64 d's per thread

    // xTv[d*2 + h] = {x[g=4h..4h+3] at dim d}
    const f4* xTv = (const f4*)(&xT[0][0]);

    f2 acc1[4] = {{0.f,0.f},{0.f,0.f},{0.f,0.f},{0.f,0.f}};
    float accL[G] = {0.f,0.f,0.f,0.f,0.f,0.f,0.f,0.f};

    for (int grp = 0; grp < 4; ++grp) {
        f2 prod[4] = {{1.f,1.f},{1.f,1.f},{1.f,1.f},{1.f,1.f}};
        #pragma unroll
        for (int q = 0; q < 4; ++q) {
            const int d0 = dbase + (grp * 4 + q) * 4;
            const float* base = CA8 + ((size_t)(d0 >> 2) * Kc + kk) * 8;
            f4 c4 = *(const f4*)base;          // dwordx4, coalesced over kk
            f4 A4 = *(const f4*)(base + 4);    // same addr + imm 16
            #pragma unroll
            for (int h = 0; h < 2; ++h) {      // g-halves: rows 4h..4h+3
                f4 xa = xTv[(d0 + 0) * 2 + h]; // LDS b128 broadcast (d uniform)
                f4 xb = xTv[(d0 + 1) * 2 + h];
                f4 xc = xTv[(d0 + 2) * 2 + h];
                f4 xd = xTv[(d0 + 3) * 2 + h];
                #pragma unroll
                for (int pp2 = 0; pp2 < 2; ++pp2) {
                    const int p = h * 2 + pp2;
                    const int o = pp2 * 2;
                    f2 ep = e2[p], nap = na2[p];
                    f2 x0 = {xa[o], xa[o+1]};
                    f2 x1 = {xb[o], xb[o+1]};
                    f2 x2 = {xc[o], xc[o+1]};
                    f2 x3 = {xd[o], xd[o+1]};
                    f2 v0 = fma2(ep, splat2(A4[0]), one2);   // var in [0.25,1]
                    f2 v1 = fma2(ep, splat2(A4[1]), one2);
                    f2 v2 = fma2(ep, splat2(A4[2]), one2);
                    f2 v3 = fma2(ep, splat2(A4[3]), one2);
                    f2 f0 = fma2(nap, splat2(c4[0]), x0);
                    f2 f1 = fma2(nap, splat2(c4[1]), x1);
                    f2 f2_ = fma2(nap, splat2(c4[2]), x2);
                    f2 f3 = fma2(nap, splat2(c4[3]), x3);
                    f2 s0 = f0 * f0, s1 = f1 * f1, s2 = f2_ * f2_, s3 = f3 * f3;
                    f2 d01 = v0 * v1, d23 = v2 * v3;
                    f2 n01 = fma2(s1, v0, s0 * v1);
                    f2 n23 = fma2(s3, v2, s2 * v3);
                    f2 den = d01 * d23;                      // >= 0.25^4
                    f2 num = fma2(n23, d01, n01 * d23);
                    f2 r = {__builtin_amdgcn_rcpf(den[0]),
                            __builtin_amdgcn_rcpf(den[1])};
                    acc1[p] = fma2(num, r, acc1[p]);
                    prod[p] = prod[p] * den;
                }
            }
        }
        #pragma unroll
        for (int p = 0; p < 4; ++p) {
            accL[2*p  ] += __log2f(prod[p][0]);  // 1 log per 16 d per g
            accL[2*p+1] += __log2f(prod[p][1]);
        }
    }
    #pragma unroll
    for (int p = 0; p < 4; ++p) {
        part1[2*p  ][quarter][kk] = acc1[p][0];
        part1[2*p+1][quarter][kk] = acc1[p][1];
    }
    #pragma unroll
    for (int g = 0; g < G; ++g)
        partL[g][quarter][kk] = accL[g];
    __syncthreads();

    // ------- softmax over k (threads < 256: g-half per 128 threads) -------
    float lpv[4];
    const int kk2 = tid & (Kc - 1);
    if (tid < 256) {
        float lw = __logf(weights[kk2]);
        const int gh = tid >> 7;                 // 0 or 1 -> rows 4gh..4gh+3
        #pragma unroll
        for (int j = 0; j < 4; ++j) {
            const int g = gh * 4 + j;
            float S1 = (part1[g][0][kk2] + part1[g][1][kk2])
                     + (part1[g][2][kk2] + part1[g][3][kk2]);
            float S2 = (partL[g][0][kk2] + partL[g][1][kk2])
                     + (partL[g][2][kk2] + partL[g][3][kk2]);
            lpv[j] = fmaf(-0.5f, S1, fmaf(-88.72283911167299f, S2, lw)); // 128*ln2
            float m = lpv[j];
            #pragma unroll
            for (int off = 32; off > 0; off >>= 1)
                m = fmaxf(m, __shfl_xor(m, off, 64));
            if ((tid & 63) == 0) wmax[g][(tid >> 6) & 1] = m;
        }
    }
    __syncthreads();
    if (tid < 256) {
        const int gh = tid >> 7;
        #pragma unroll
        for (int j = 0; j < 4; ++j) {
            const int g = gh * 4 + j;
            float m  = fmaxf(wmax[g][0], wmax[g][1]);
            float pe = __expf(lpv[j] - m);
            peT[kk2][g] = pe;                  // unnormalized; 1/Z in epilogue
            float s = pe;
            #pragma unroll
            for (int off = 32; off > 0; off >>= 1)
                s += __shfl_xor(s, off, 64);
            if ((tid & 63) == 0) wsum[g][(tid >> 6) & 1] = s;
        }
    }
    __syncthreads();

    // ---------------- pass 2: thread = (k-half, d) ----------------
    const int dd    = tid & (Dc - 1);
    const int khalf = tid >> 8;                // 0 or 1
    f4 xlo = xTv[dd * 2], xhi = xTv[dd * 2 + 1];
    f2 xp[4] = {{xlo[0], xlo[1]}, {xlo[2], xlo[3]},
                {xhi[0], xhi[1]}, {xhi[2], xhi[3]}};
    f2 O[4] = {{0.f,0.f},{0.f,0.f},{0.f,0.f},{0.f,0.f}};
    const f4* peTv = (const f4*)(&peT[0][0]);  // peTv[k*2 + h]
    const f2* pp = P2 + dd;

    const int kq0 = khalf * 16;
    for (int kq = kq0; kq < kq0 + 16; ++kq) {
        const int k0 = kq * 4;
        f2 ca0 = pp[(k0 + 0) * Dc];            // dwordx2 {c,A}, coalesced
        f2 ca1 = pp[(k0 + 1) * Dc];
        f2 ca2 = pp[(k0 + 2) * Dc];
        f2 ca3 = pp[(k0 + 3) * Dc];
        #pragma unroll
        for (int h = 0; h < 2; ++h) {
            f4 pa = peTv[(k0 + 0) * 2 + h];    // LDS b128 broadcast
            f4 pb = peTv[(k0 + 1) * 2 + h];
            f4 pc = peTv[(k0 + 2) * 2 + h];
            f4 pd = peTv[(k0 + 3) * 2 + h];
            #pragma unroll
            for (int pp2 = 0; pp2 < 2; ++pp2) {
                const int p = h * 2 + pp2;
                const int o = pp2 * 2;
                f2 ep = e2[p], nap = na2[p];
                f2 v0 = fma2(ep, splat2(ca0[1]), one2);
                f2 v1 = fma2(ep, splat2(ca1[1]), one2);
                f2 v2 = fma2(ep, splat2(ca2[1]), one2);
                f2 v3 = fma2(ep, splat2(ca3[1]), one2);
                f2 f0 = fma2(nap, splat2(ca0[0]), xp[p]);
                f2 f1 = fma2(nap, splat2(ca1[0]), xp[p]);
                f2 f2_ = fma2(nap, splat2(ca2[0]), xp[p]);
                f2 f3 = fma2(nap, splat2(ca3[0]), xp[p]);
                f2 u0 = (f2){pa[o], pa[o+1]} * f0;
                f2 u1 = (f2){pb[o], pb[o+1]} * f1;
                f2 u2 = (f2){pc[o], pc[o+1]} * f2_;
                f2 u3 = (f2){pd[o], pd[o+1]} * f3;
                f2 d01 = v0 * v1, d23 = v2 * v3;
                f2 n01 = fma2(u1, v0, u0 * v1);
                f2 n23 = fma2(u3, v2, u2 * v3);
                f2 den = d01 * d23;
                f2 num = fma2(n23, d01, n01 * d23);
                f2 r = {__builtin_amdgcn_rcpf(den[0]),
                        __builtin_amdgcn_rcpf(den[1])};
                O[p] = fma2(num, r, O[p]);
            }
        }
    }

    if (khalf) {
        #pragma unroll
        for (int p = 0; p < 4; ++p) {
            #pragma unroll
            for (int j = 0; j < 2; ++j)
                Opart[2*p + j][dd] = O[p][j];
        }
    }
    __syncthreads();
    if (!khalf) {
        #pragma unroll
        for (int p = 0; p < 4; ++p) {
            #pragma unroll
            for (int j = 0; j < 2; ++j) {
                const int g = 2 * p + j;
                float Z  = wsum[g][0] + wsum[g][1];
                float sg = sqrtf(1.0f - e2[p][j]);
                float Ov = O[p][j] + Opart[g][dd];   // (k-half0) + (k-half1)
                out[(b0 + g) * Dc + dd] = sg * __builtin_amdgcn_rcpf(Z) * Ov;
            }
        }
    }
}

extern "C" void kernel_launch(void* const* d_in, const int* in_sizes, int n_in,
                              void* d_out, int out_size, void* d_ws, size_t ws_size,
                              hipStream_t stream) {
    const float* x       = (const float*)d_in[0];
    const float* t       = (const float*)d_in[1];
    const float* centers = (const float*)d_in[2];
    const float* stds    = (const float*)d_in[3];
    const float* weights = (const float*)d_in[4];
    float* outp = (float*)d_out;

    float* CA8 = (float*)d_ws;                    // [D/4][K][8]  (256 KB)
    f2*    P2  = (f2*)(CA8 + Kc * Dc * 2);        // [K][D] {c,A} (256 KB)

    const int B = in_sizes[1];                    // 4096

    prep_kernel<<<(Kc * Dc + 255) / 256, 256, 0, stream>>>(centers, stds, CA8, P2);
    score_kernel<<<B / G, 512, 0, stream>>>(x, t, weights, CA8, P2, outp);
}